// Round 4
// baseline (300.054 us; speedup 1.0000x reference)
//
#include <hip/hip_runtime.h>
#include <hip/hip_fp16.h>

// PairwiseMamba: 2304 independent mamba scans (T=1024, d_inner=4, d_state=8).
// R10 = fine-grained rounds. R9 refuted "fewer waves, flat round" (52us, 62%
// busy); R6's 43us decomposes as: 9 blocks/CU supply vs 8-block (32-wave)
// residency -> round 1 full + round 2 = ONE block/CU at 12% occupancy, i.e.
// ~2x block-time total; time-avg VALUBusy (90%+45%)/2 ~ 67% matches measured.
// Fix: halve the round quantum. NSEGS=16 segments of 64 steps, 512-thr/8-wave
// blocks, one sequence per block (no cross-block math). LDS 37.9KB/block ->
// exactly 4 blocks/CU = 32 waves/CU (LDS and wave caps hit together, full
// occupancy in main rounds). Supply 9/CU over 4 -> 2 full rounds + 1/4-round
// tail ~ 1.25x block-time vs 2.0x today. launch_bounds(512,8) caps VGPR at 64
// (using ~40-48; R8 lesson: verify WRITE_SIZE stays 144KB = no spill).
// Staging/numerics identical to R9 (0-conflict layout, fma_mix f32 products).

typedef float v2f __attribute__((ext_vector_type(2)));

#define TT 1024
#define TC 32
#define NSEGS 16
#define SEGLEN (TT / NSEGS)            // 64
#define NCHUNK (SEGLEN / TC)           // 2
#define NUM_PAIRS 36
#define NSEQ 2304

// per-(wave,half) staging layout (float/uint slots), rows stride 36 (144B):
// DT [0,144): f32 [d][t]   DS [144,288): u32 half2(dtx,sz) [d][t]
// BC [288,576): u32 half2(B,C) [s][t]
#define ROWS 36
#define DS_OFF 144
#define BC_OFF 288
#define UNIT_STRIDE 592                // floats; %32==16 -> wave halves bank-disjoint
#define STAGE_TOTAL (16 * UNIT_STRIDE) // 9472 floats = 37888 B

__device__ __forceinline__ float fast_silu(float v) {
    float e = __builtin_amdgcn_exp2f(v * -1.4426950408889634f);
    return v * __builtin_amdgcn_rcpf(1.0f + e);
}
// softplus, direct form: log(1+exp(v)). Safe: |v| <~ 20 here.
__device__ __forceinline__ float fast_softplus(float v) {
    float e = __builtin_amdgcn_exp2f(v * 1.4426950408889634f);
    return __builtin_amdgcn_logf(1.0f + e) * 0.6931471805599453f;
}
__device__ __forceinline__ uint pk_h2(float a, float b) {
    return __builtin_bit_cast(uint, __builtin_amdgcn_cvt_pkrtz(a, b));
}

__global__ __launch_bounds__(512, 8)
void pm_kernel(const float* __restrict__ raw,        // (N,2,T)
               const float* __restrict__ in_proj_w,  // (8,2)
               const float* __restrict__ conv_w,     // (4,2)
               const float* __restrict__ conv_b,     // (4)
               const float* __restrict__ x_proj_w,   // (17,4)
               const float* __restrict__ dt_proj_w,  // (4,1)
               const float* __restrict__ dt_proj_b,  // (4)
               const float* __restrict__ A_log,      // (4,8)
               const float* __restrict__ D_skip,     // (4)
               const float* __restrict__ out_proj_w, // (2,4)
               const float* __restrict__ proj_w,     // (16,2)
               const float* __restrict__ proj_b,     // (16)
               float* __restrict__ out)              // (64,16), pre-zeroed
{
    __shared__ float lds[STAGE_TOTAL];

    const int tid  = threadIdx.x;
    const int wid  = tid >> 6;        // wave 0..7
    const int lane = tid & 63;
    const int half = lane >> 5;
    const int lh   = lane & 31;       // pointwise: t-in-chunk; scan: ds = d*8+s
    const int g    = wid * 2 + half;  // segment 0..15 of THIS block's sequence
    const int n    = blockIdx.x;      // one sequence per block
    const float* rp = raw + (size_t)n * (2 * TT);

    float* hb = lds + g * UNIT_STRIDE;

    // ---- weights (wave-uniform -> scalarized) ----
    // ipxy{0,1}[d] = {in_proj[d][c], in_proj[4+d][c]} : x-path / z-path pair
    v2f ipxy0[4], ipxy1[4];
#pragma unroll
    for (int d = 0; d < 4; ++d) {
        ipxy0[d] = (v2f){in_proj_w[2*d],     in_proj_w[2*(4+d)]};
        ipxy1[d] = (v2f){in_proj_w[2*d + 1], in_proj_w[2*(4+d) + 1]};
    }
    float cw0[4], cw1[4], cbv[4], dpw[4], dpb[4], Dsk[4], ow0[4], ow1[4], xp0[4];
#pragma unroll
    for (int d = 0; d < 4; ++d) {
        cw0[d] = conv_w[2*d]; cw1[d] = conv_w[2*d+1]; cbv[d] = conv_b[d];
        dpw[d] = dt_proj_w[d]; dpb[d] = dt_proj_b[d];
        Dsk[d] = D_skip[d]; ow0[d] = out_proj_w[d]; ow1[d] = out_proj_w[4+d];
        xp0[d] = x_proj_w[d];
    }
    v2f xbc[8][4];  // {x_proj_w[1+s][d], x_proj_w[9+s][d]}
#pragma unroll
    for (int s = 0; s < 8; ++s)
#pragma unroll
        for (int d = 0; d < 4; ++d)
            xbc[s][d] = (v2f){x_proj_w[4*(1+s) + d], x_proj_w[4*(9+s) + d]};

    const float LOG2E = 1.4426950408889634f;
    // scan-role constants: lane lh -> (d,s)
    const int   d_idx = lh >> 3;
    const int   s_idx = lh & 7;
    const float A2ds  = -__expf(A_log[lh]) * LOG2E;   // a = exp2(dt * A2ds)
    const v2f   a2    = (v2f){A2ds, A2ds};
    const float owd0  = out_proj_w[d_idx];
    const float owd1  = out_proj_w[4 + d_idx];

    // hoisted scan read pointers (imm offsets inside the loop)
    const float4* dp4 = (const float4*)hb + d_idx * (ROWS / 4);           // 9/row
    const uint4*  sp4 = (const uint4*)(hb + DS_OFF) + d_idx * (ROWS / 4);
    const uint4*  bp4 = (const uint4*)(hb + BC_OFF) + s_idx * (ROWS / 4);

    // segment-local affine reduction state (per ds lane)
    float A_run = 1.0f, hB = 0.0f, W = 0.0f, S = 0.0f;
    float sacc0 = 0.f, sacc1 = 0.f;                    // skip-term partials
    float zf = 0.0f;                                   // VGPR zero for fma_mix

    const int seg0 = g * SEGLEN;

    // prefetch chunk 0 raw samples (t and t-1, both channels)
    int t0 = seg0 + lh;
    float c0  = rp[t0];
    float c1  = rp[TT + t0];
    float c0m = (t0 > 0) ? rp[t0 - 1]      : 0.0f;     // causal pad at t==0
    float c1m = (t0 > 0) ? rp[TT + t0 - 1] : 0.0f;

    for (int chunk = 0; chunk < NCHUNK; ++chunk) {
        // software prefetch next chunk's raw
        float p0 = 0.f, p1 = 0.f, p0m = 0.f, p1m = 0.f;
        if (chunk + 1 < NCHUNK) {
            int tn = seg0 + (chunk + 1) * TC + lh;     // tn >= 32 -> tn-1 valid
            p0  = rp[tn];       p1  = rp[TT + tn];
            p0m = rp[tn - 1];   p1m = rp[TT + tn - 1];
        }

        // ---- pointwise: this lane handles t = seg0 + chunk*TC + lh ----
        float x[4], sz[4];
        v2f cc0 = (v2f){c0, c0}, cc1 = (v2f){c1, c1};
#pragma unroll
        for (int d = 0; d < 4; ++d) {
            v2f xv = __builtin_elementwise_fma(ipxy1[d], cc1, ipxy0[d] * cc0);
            float xm1 = ipxy0[d].x*c0m + ipxy1[d].x*c1m;
            float v   = xm1*cw0[d] + xv.x*cw1[d] + cbv[d];  // causal conv k=2
            x[d]  = fast_silu(v);
            sz[d] = fast_silu(xv.y);
        }

        float dtin = xp0[0]*x[0] + xp0[1]*x[1] + xp0[2]*x[2] + xp0[3]*x[3];

        v2f bc[8];
#pragma unroll
        for (int s = 0; s < 8; ++s) {
            v2f a = xbc[s][0] * (v2f){x[0], x[0]};
            a = __builtin_elementwise_fma(xbc[s][1], (v2f){x[1], x[1]}, a);
            a = __builtin_elementwise_fma(xbc[s][2], (v2f){x[2], x[2]}, a);
            bc[s] = __builtin_elementwise_fma(xbc[s][3], (v2f){x[3], x[3]}, a);
        }

        float dt[4];
#pragma unroll
        for (int d = 0; d < 4; ++d) {
            dt[d] = fast_softplus(dtin*dpw[d] + dpb[d]);
            float g2 = x[d] * Dsk[d] * sz[d];              // skip term
            sacc0 = fmaf(g2, ow0[d], sacc0);
            sacc1 = fmaf(g2, ow1[d], sacc1);
        }

        // stage: DT b32, DS b32, BC b32 rows (stride 36; all <=2-way = free;
        // measured 0 conflicts in R8/R9)
        uint* dsw = (uint*)(hb + DS_OFF) + lh;
#pragma unroll
        for (int d = 0; d < 4; ++d) {
            hb[d*ROWS + lh] = dt[d];
            dsw[d*ROWS] = pk_h2(dt[d]*x[d], sz[d]);
        }
        uint* bcw = (uint*)(hb + BC_OFF) + lh;
#pragma unroll
        for (int s = 0; s < 8; ++s)
            bcw[s * ROWS] = pk_h2(bc[s].x, bc[s].y);

        // ---- scan: lane owns (d_idx, s_idx); local affine reduction ----
        // (same-wave LDS RAW: per-wave in-order LDS + compiler waitcnt)
        // b = dtx*B, q = sz*C via v_fma_mix_f32 (f16 srcs, f32 product)
#define SCAN_STEP(TA, DSW, BCW) do {                                         \
            uint _ud = (DSW);                                                \
            uint _ub = (BCW);                                                \
            float _b, _q;                                                    \
            asm("v_fma_mix_f32 %0, %1, %2, %3 op_sel_hi:[1,1,0]"             \
                : "=v"(_b) : "v"(_ud), "v"(_ub), "v"(zf));                   \
            asm("v_fma_mix_f32 %0, %1, %2, %3 op_sel:[1,1,0] op_sel_hi:[1,1,0]" \
                : "=v"(_q) : "v"(_ud), "v"(_ub), "v"(zf));                   \
            float _a = __builtin_amdgcn_exp2f(TA);                           \
            A_run *= _a;                   /* running product  П a        */ \
            hB = fmaf(_a, hB, _b);         /* local scan, h_in = 0        */ \
            W  = fmaf(A_run, _q, W);       /* h_in-coupling coefficient   */ \
            S  = fmaf(hB, _q, S);          /* h_in-independent part       */ \
        } while (0)

#pragma unroll
        for (int j = 0; j < TC / 4; ++j) {              // 4 t per iter
            float4 ft = dp4[j];                         // dt for t=4j..4j+3
            uint4  ds = sp4[j];                         // half2(dtx,sz)
            uint4  bq = bp4[j];                         // half2(B,C)
            v2f t01 = (v2f){ft.x, ft.y} * a2;           // packed dt*A2ds
            v2f t23 = (v2f){ft.z, ft.w} * a2;
            SCAN_STEP(t01.x, ds.x, bq.x);
            SCAN_STEP(t01.y, ds.y, bq.y);
            SCAN_STEP(t23.x, ds.z, bq.z);
            SCAN_STEP(t23.y, ds.w, bq.w);
        }
#undef SCAN_STEP

        c0 = p0; c1 = p1; c0m = p0m; c1m = p1m;
    }

    // ---- cross-segment combine (aliases dead staging LDS, post-barrier) ----
    __syncthreads();
    float2* comb = (float2*)lds;                       // 16*32 float2 = 1024 floats
    comb[g*32 + lh] = make_float2(A_run, hB);
    __syncthreads();

    // compose the segments before g to get this segment's h_in (g wave-uniform
    // per half; exec-masked loop, max 15 iters)
    float h_in = 0.0f;
#pragma unroll
    for (int gg = 0; gg < NSEGS - 1; ++gg) {
        if (gg < g) {
            float2 abg = comb[gg*32 + lh];
            h_in = fmaf(abg.x, h_in, abg.y);
        }
    }

    float F = fmaf(h_in, W, S);          // this segment's Σ_t h_t q_t for (d,s)
    float tot0 = fmaf(F, owd0, sacc0);
    float tot1 = fmaf(F, owd1, sacc1);
#pragma unroll
    for (int m = 16; m >= 1; m >>= 1) {  // reduce within the 32-lane half
        tot0 += __shfl_xor(tot0, m, 64);
        tot1 += __shfl_xor(tot1, m, 64);
    }
    float* part = lds + 1024;            // past comb region
    if (lh == 0) {
        part[g*2]     = tot0;
        part[g*2 + 1] = tot1;
    }
    __syncthreads();

    // wave 0 lanes 0-15: sum segment partials, head projection, mean over pairs
    if (tid < 16) {
        float f0 = 0.f, f1 = 0.f;
#pragma unroll
        for (int gg = 0; gg < NSEGS; ++gg) {
            f0 += part[gg*2];
            f1 += part[gg*2 + 1];
        }
        f0 *= (1.0f / (float)TT);
        f1 *= (1.0f / (float)TT);
        float pv = f0*proj_w[2*tid] + f1*proj_w[2*tid + 1] + proj_b[tid];
        pv = fmaxf(pv, 0.0f);
        atomicAdd(out + (n / NUM_PAIRS) * 16 + tid, pv * (1.0f / NUM_PAIRS));
    }
}

extern "C" void kernel_launch(void* const* d_in, const int* in_sizes, int n_in,
                              void* d_out, int out_size, void* d_ws, size_t ws_size,
                              hipStream_t stream)
{
    const float* raw        = (const float*)d_in[0];
    const float* in_proj_w  = (const float*)d_in[1];
    const float* conv_w     = (const float*)d_in[2];
    const float* conv_b     = (const float*)d_in[3];
    const float* x_proj_w   = (const float*)d_in[4];
    const float* dt_proj_w  = (const float*)d_in[5];
    const float* dt_proj_b  = (const float*)d_in[6];
    const float* A_log      = (const float*)d_in[7];
    const float* D_skip     = (const float*)d_in[8];
    const float* out_proj_w = (const float*)d_in[9];
    const float* proj_w     = (const float*)d_in[10];
    const float* proj_b     = (const float*)d_in[11];

    // d_out is re-poisoned before every timed replay; zero it (atomicAdd sink)
    hipMemsetAsync(d_out, 0, (size_t)out_size * sizeof(float), stream);

    pm_kernel<<<dim3(NSEQ), dim3(512), 0, stream>>>(
        raw, in_proj_w, conv_w, conv_b, x_proj_w, dt_proj_w, dt_proj_b,
        A_log, D_skip, out_proj_w, proj_w, proj_b, (float*)d_out);
}

// Round 5
// 118.925 us; speedup vs baseline: 2.5231x; 2.5231x over previous
//
#include <hip/hip_runtime.h>
#include <hip/hip_fp16.h>

// PairwiseMamba: 2304 independent mamba scans (T=1024, d_inner=4, d_state=8).
// R11 = true VALU-instruction diet in the proven R6/R7 launch shape.
// History: R7 cut LDS insts (neutral -> LDS pipe not binding); R8/R10 tight
// launch bounds spilled (630MB/1GB scratch traffic); R9 halved waves (worse,
// 62% busy). Busy-vs-waves saturates at ~0.75-0.8 => shared/per-issue cap,
// and a VALU diet was never actually tested. This round cuts VALU insts ~10%:
//  (a) scan state as f32 pairs: hA={hB,A_run}, SW={S,W}; the two output
//      accumulations fuse into ONE v_pk_fma_f32 (SW += hA*{q,q}): 7->6/step.
//  (b) sacc pair: {sacc0,sacc1} += {g2,g2}*{ow0,ow1}[d]: 8 fma -> 4 pk_fma.
//  (c) dt-preact packed over d-pairs: 4 fma -> 2 pk_fma.
// Shape: 256 thr / launch_bounds(256,4) (only proven no-spill env), NSEGS=8,
// one sequence per block, grid 2304 (9 blocks/CU supply, 8 resident).
// Staging: R8/R9's measured-0-conflict layout, DT f32[4][36] / DS u32[4][36]
// half2(dtx,sz) / BC u32[8][36] half2(B,C); unit stride 592 (%32==16 ->
// halves bank-disjoint); 18944 B/block -> 8 blocks = 151.5 KB/CU (fits).
// Scan reads 3x ds_read_b128 per 4 steps; b=dtx*B, q=sz*C via v_fma_mix_f32.
// Hypothesis test: if VALU-issue-bound -> ~39-40us; if neutral -> trans pipe.

typedef float v2f __attribute__((ext_vector_type(2)));

#define TT 1024
#define TC 32
#define NSEGS 8
#define SEGLEN (TT / NSEGS)            // 128
#define NCHUNK (SEGLEN / TC)           // 4
#define NUM_PAIRS 36
#define NSEQ 2304

// per-(wave,half) staging layout (float/uint slots), rows stride 36 (144B):
// DT [0,144): f32 [d][t]   DS [144,288): u32 half2(dtx,sz) [d][t]
// BC [288,576): u32 half2(B,C) [s][t]
#define ROWS 36
#define DS_OFF 144
#define BC_OFF 288
#define UNIT_STRIDE 592                // floats; %32==16 -> halves bank-disjoint
#define STAGE_TOTAL (8 * UNIT_STRIDE)  // 4736 floats = 18944 B

__device__ __forceinline__ float fast_silu(float v) {
    float e = __builtin_amdgcn_exp2f(v * -1.4426950408889634f);
    return v * __builtin_amdgcn_rcpf(1.0f + e);
}
// softplus, direct form: log(1+exp(v)). Safe: |v| <~ 20 here.
__device__ __forceinline__ float fast_softplus(float v) {
    float e = __builtin_amdgcn_exp2f(v * 1.4426950408889634f);
    return __builtin_amdgcn_logf(1.0f + e) * 0.6931471805599453f;
}
__device__ __forceinline__ uint pk_h2(float a, float b) {
    return __builtin_bit_cast(uint, __builtin_amdgcn_cvt_pkrtz(a, b));
}

__global__ __launch_bounds__(256, 4)
void pm_kernel(const float* __restrict__ raw,        // (N,2,T)
               const float* __restrict__ in_proj_w,  // (8,2)
               const float* __restrict__ conv_w,     // (4,2)
               const float* __restrict__ conv_b,     // (4)
               const float* __restrict__ x_proj_w,   // (17,4)
               const float* __restrict__ dt_proj_w,  // (4,1)
               const float* __restrict__ dt_proj_b,  // (4)
               const float* __restrict__ A_log,      // (4,8)
               const float* __restrict__ D_skip,     // (4)
               const float* __restrict__ out_proj_w, // (2,4)
               const float* __restrict__ proj_w,     // (16,2)
               const float* __restrict__ proj_b,     // (16)
               float* __restrict__ out)              // (64,16), pre-zeroed
{
    __shared__ float lds[STAGE_TOTAL];

    const int tid  = threadIdx.x;
    const int wid  = tid >> 6;        // wave 0..3
    const int lane = tid & 63;
    const int half = lane >> 5;
    const int lh   = lane & 31;       // pointwise: t-in-chunk; scan: ds = d*8+s
    const int g    = wid * 2 + half;  // segment 0..7 of THIS block's sequence
    const int n    = blockIdx.x;      // one sequence per block
    const float* rp = raw + (size_t)n * (2 * TT);

    float* hb = lds + g * UNIT_STRIDE;

    // ---- weights (wave-uniform -> scalarized) ----
    // ipxy{0,1}[d] = {in_proj[d][c], in_proj[4+d][c]} : x-path / z-path pair
    v2f ipxy0[4], ipxy1[4];
#pragma unroll
    for (int d = 0; d < 4; ++d) {
        ipxy0[d] = (v2f){in_proj_w[2*d],     in_proj_w[2*(4+d)]};
        ipxy1[d] = (v2f){in_proj_w[2*d + 1], in_proj_w[2*(4+d) + 1]};
    }
    float cw0[4], cw1[4], cbv[4], Dsk[4], xp0[4];
#pragma unroll
    for (int d = 0; d < 4; ++d) {
        cw0[d] = conv_w[2*d]; cw1[d] = conv_w[2*d+1]; cbv[d] = conv_b[d];
        Dsk[d] = D_skip[d];   xp0[d] = x_proj_w[d];
    }
    // packed weight pairs for the diet
    const v2f DPW01 = (v2f){dt_proj_w[0], dt_proj_w[1]};
    const v2f DPW23 = (v2f){dt_proj_w[2], dt_proj_w[3]};
    const v2f DPB01 = (v2f){dt_proj_b[0], dt_proj_b[1]};
    const v2f DPB23 = (v2f){dt_proj_b[2], dt_proj_b[3]};
    v2f OWp[4];   // {out_proj[0][d], out_proj[1][d]}
#pragma unroll
    for (int d = 0; d < 4; ++d)
        OWp[d] = (v2f){out_proj_w[d], out_proj_w[4 + d]};

    v2f xbc[8][4];  // {x_proj_w[1+s][d], x_proj_w[9+s][d]}
#pragma unroll
    for (int s = 0; s < 8; ++s)
#pragma unroll
        for (int d = 0; d < 4; ++d)
            xbc[s][d] = (v2f){x_proj_w[4*(1+s) + d], x_proj_w[4*(9+s) + d]};

    const float LOG2E = 1.4426950408889634f;
    // scan-role constants: lane lh -> (d,s)
    const int   d_idx = lh >> 3;
    const int   s_idx = lh & 7;
    const float A2ds  = -__expf(A_log[lh]) * LOG2E;   // a = exp2(dt * A2ds)
    const v2f   a2    = (v2f){A2ds, A2ds};
    const float owd0  = out_proj_w[d_idx];
    const float owd1  = out_proj_w[4 + d_idx];

    // hoisted scan read pointers (imm offsets inside the loop)
    const float4* dp4 = (const float4*)hb + d_idx * (ROWS / 4);           // 9/row
    const uint4*  sp4 = (const uint4*)(hb + DS_OFF) + d_idx * (ROWS / 4);
    const uint4*  bp4 = (const uint4*)(hb + BC_OFF) + s_idx * (ROWS / 4);

    // segment-local affine reduction state (per ds lane), packed:
    // hA = {hB, A_run}   SW = {S, W}   SACC = {sacc0, sacc1}
    v2f hA = (v2f){0.0f, 1.0f};
    v2f SW = (v2f){0.0f, 0.0f};
    v2f SACC = (v2f){0.0f, 0.0f};
    float zf = 0.0f;                                   // VGPR zero for fma_mix

    const int seg0 = g * SEGLEN;

    // prefetch chunk 0 raw samples (t and t-1, both channels)
    int t0 = seg0 + lh;
    float c0  = rp[t0];
    float c1  = rp[TT + t0];
    float c0m = (t0 > 0) ? rp[t0 - 1]      : 0.0f;     // causal pad at t==0
    float c1m = (t0 > 0) ? rp[TT + t0 - 1] : 0.0f;

    for (int chunk = 0; chunk < NCHUNK; ++chunk) {
        // software prefetch next chunk's raw
        float p0 = 0.f, p1 = 0.f, p0m = 0.f, p1m = 0.f;
        if (chunk + 1 < NCHUNK) {
            int tn = seg0 + (chunk + 1) * TC + lh;     // tn >= 32 -> tn-1 valid
            p0  = rp[tn];       p1  = rp[TT + tn];
            p0m = rp[tn - 1];   p1m = rp[TT + tn - 1];
        }

        // ---- pointwise: this lane handles t = seg0 + chunk*TC + lh ----
        float x[4], sz[4];
        v2f cc0 = (v2f){c0, c0}, cc1 = (v2f){c1, c1};
#pragma unroll
        for (int d = 0; d < 4; ++d) {
            v2f xv = __builtin_elementwise_fma(ipxy1[d], cc1, ipxy0[d] * cc0);
            float xm1 = ipxy0[d].x*c0m + ipxy1[d].x*c1m;
            float v   = xm1*cw0[d] + xv.x*cw1[d] + cbv[d];  // causal conv k=2
            x[d]  = fast_silu(v);
            sz[d] = fast_silu(xv.y);
        }

        float dtin = xp0[0]*x[0] + xp0[1]*x[1] + xp0[2]*x[2] + xp0[3]*x[3];

        v2f bc[8];
#pragma unroll
        for (int s = 0; s < 8; ++s) {
            v2f a = xbc[s][0] * (v2f){x[0], x[0]};
            a = __builtin_elementwise_fma(xbc[s][1], (v2f){x[1], x[1]}, a);
            a = __builtin_elementwise_fma(xbc[s][2], (v2f){x[2], x[2]}, a);
            bc[s] = __builtin_elementwise_fma(xbc[s][3], (v2f){x[3], x[3]}, a);
        }

        // dt preactivation, packed over d-pairs
        v2f dts = (v2f){dtin, dtin};
        v2f ud01 = __builtin_elementwise_fma(DPW01, dts, DPB01);
        v2f ud23 = __builtin_elementwise_fma(DPW23, dts, DPB23);
        float dt[4];
        dt[0] = fast_softplus(ud01.x);
        dt[1] = fast_softplus(ud01.y);
        dt[2] = fast_softplus(ud23.x);
        dt[3] = fast_softplus(ud23.y);
#pragma unroll
        for (int d = 0; d < 4; ++d) {
            float g2 = x[d] * Dsk[d] * sz[d];              // skip term
            SACC = __builtin_elementwise_fma((v2f){g2, g2}, OWp[d], SACC);
        }

        // stage: DT b32, DS b32, BC b32 rows (stride 36; all <=2-way = free;
        // measured 0 conflicts in R8/R9)
        uint* dsw = (uint*)(hb + DS_OFF) + lh;
#pragma unroll
        for (int d = 0; d < 4; ++d) {
            hb[d*ROWS + lh] = dt[d];
            dsw[d*ROWS] = pk_h2(dt[d]*x[d], sz[d]);
        }
        uint* bcw = (uint*)(hb + BC_OFF) + lh;
#pragma unroll
        for (int s = 0; s < 8; ++s)
            bcw[s * ROWS] = pk_h2(bc[s].x, bc[s].y);

        // ---- scan: lane owns (d_idx, s_idx); local affine reduction ----
        // (same-wave LDS RAW: per-wave in-order LDS + compiler waitcnt)
        // b = dtx*B, q = sz*C via v_fma_mix_f32 (f16 srcs, f32 product);
        // hA = {hB, A_run}: hB = a*hB + b (scalar lo), A_run *= a (scalar hi);
        // SW = {S, W} += {hB, A_run} * {q,q} -> one v_pk_fma_f32.
#define SCAN_STEP(TA, DSW, BCW) do {                                         \
            uint _ud = (DSW);                                                \
            uint _ub = (BCW);                                                \
            float _b, _q;                                                    \
            asm("v_fma_mix_f32 %0, %1, %2, %3 op_sel_hi:[1,1,0]"             \
                : "=v"(_b) : "v"(_ud), "v"(_ub), "v"(zf));                   \
            asm("v_fma_mix_f32 %0, %1, %2, %3 op_sel:[1,1,0] op_sel_hi:[1,1,0]" \
                : "=v"(_q) : "v"(_ud), "v"(_ub), "v"(zf));                   \
            float _a = __builtin_amdgcn_exp2f(TA);                           \
            hA.x = fmaf(_a, hA.x, _b);     /* local scan, h_in = 0        */ \
            hA.y *= _a;                    /* running product  П a        */ \
            SW = __builtin_elementwise_fma(hA, (v2f){_q, _q}, SW);           \
        } while (0)

#pragma unroll
        for (int j = 0; j < TC / 4; ++j) {              // 4 t per iter
            float4 ft = dp4[j];                         // dt for t=4j..4j+3
            uint4  ds = sp4[j];                         // half2(dtx,sz)
            uint4  bq = bp4[j];                         // half2(B,C)
            v2f t01 = (v2f){ft.x, ft.y} * a2;           // packed dt*A2ds
            v2f t23 = (v2f){ft.z, ft.w} * a2;
            SCAN_STEP(t01.x, ds.x, bq.x);
            SCAN_STEP(t01.y, ds.y, bq.y);
            SCAN_STEP(t23.x, ds.z, bq.z);
            SCAN_STEP(t23.y, ds.w, bq.w);
        }
#undef SCAN_STEP

        c0 = p0; c1 = p1; c0m = p0m; c1m = p1m;
    }

    // ---- cross-segment combine (aliases dead staging LDS, post-barrier) ----
    __syncthreads();
    float2* comb = (float2*)lds;                       // 8*32 float2 = 512 floats
    comb[g*32 + lh] = make_float2(hA.y, hA.x);         // {A_run, hB}
    __syncthreads();

    // compose the segments before g to get this segment's h_in (g wave-uniform
    // per half; exec-masked loop, max 7 iters)
    float h_in = 0.0f;
#pragma unroll
    for (int gg = 0; gg < NSEGS - 1; ++gg) {
        if (gg < g) {
            float2 abg = comb[gg*32 + lh];
            h_in = fmaf(abg.x, h_in, abg.y);
        }
    }

    float F = fmaf(h_in, SW.y, SW.x);    // this segment's Σ_t h_t q_t for (d,s)
    float tot0 = fmaf(F, owd0, SACC.x);
    float tot1 = fmaf(F, owd1, SACC.y);
#pragma unroll
    for (int m = 16; m >= 1; m >>= 1) {  // reduce within the 32-lane half
        tot0 += __shfl_xor(tot0, m, 64);
        tot1 += __shfl_xor(tot1, m, 64);
    }
    float* part = lds + 512;             // past comb region
    if (lh == 0) {
        part[g*2]     = tot0;
        part[g*2 + 1] = tot1;
    }
    __syncthreads();

    // wave 0 lanes 0-15: sum segment partials, head projection, mean over pairs
    if (tid < 16) {
        float f0 = 0.f, f1 = 0.f;
#pragma unroll
        for (int gg = 0; gg < NSEGS; ++gg) {
            f0 += part[gg*2];
            f1 += part[gg*2 + 1];
        }
        f0 *= (1.0f / (float)TT);
        f1 *= (1.0f / (float)TT);
        float pv = f0*proj_w[2*tid] + f1*proj_w[2*tid + 1] + proj_b[tid];
        pv = fmaxf(pv, 0.0f);
        atomicAdd(out + (n / NUM_PAIRS) * 16 + tid, pv * (1.0f / NUM_PAIRS));
    }
}

extern "C" void kernel_launch(void* const* d_in, const int* in_sizes, int n_in,
                              void* d_out, int out_size, void* d_ws, size_t ws_size,
                              hipStream_t stream)
{
    const float* raw        = (const float*)d_in[0];
    const float* in_proj_w  = (const float*)d_in[1];
    const float* conv_w     = (const float*)d_in[2];
    const float* conv_b     = (const float*)d_in[3];
    const float* x_proj_w   = (const float*)d_in[4];
    const float* dt_proj_w  = (const float*)d_in[5];
    const float* dt_proj_b  = (const float*)d_in[6];
    const float* A_log      = (const float*)d_in[7];
    const float* D_skip     = (const float*)d_in[8];
    const float* out_proj_w = (const float*)d_in[9];
    const float* proj_w     = (const float*)d_in[10];
    const float* proj_b     = (const float*)d_in[11];

    // d_out is re-poisoned before every timed replay; zero it (atomicAdd sink)
    hipMemsetAsync(d_out, 0, (size_t)out_size * sizeof(float), stream);

    pm_kernel<<<dim3(NSEQ), dim3(256), 0, stream>>>(
        raw, in_proj_w, conv_w, conv_b, x_proj_w, dt_proj_w, dt_proj_b,
        A_log, D_skip, out_proj_w, proj_w, proj_b, (float*)d_out);
}

// Round 6
// 117.089 us; speedup vs baseline: 2.5626x; 1.0157x over previous
//
#include <hip/hip_runtime.h>
#include <hip/hip_fp16.h>

// PairwiseMamba: 2304 independent mamba scans (T=1024, d_inner=4, d_state=8).
// R12 = revert to the R6 champion (best measured: 43.2us kernel / 116.3us
// harness). Session post-mortem of R7-R11:
//   - VALUBusy x dur is CONSERVED ~30us across all configs (R6 30.7, R7 30.4,
//     R9 32.4, R11 29.3) -> fixed VALU+trans work, packing ceiling ~0.72,
//     floor ~42-43us. R6 sits on it.
//   - R7 LDS-inst diet: neutral (LDS pipe not binding).
//   - R8/R10 pipelining + tight launch bounds: scratch spill (0.4-1GB traffic).
//   - R9 fewer waves: worse (62% busy at 4.5 waves/SIMD).
//   - R11 v2f VALU diet: 64 VGPR + 35MB scratch -> 47.2us regression.
// Scan step is already minimal (1 pk-mul + 1 exp2 + 2 fma_mix + 3 fma); the
// exp2 per (d,s,t) is irreducible without losing to cndmask power ladders.
// This is the structural ceiling for this op on gfx950: VALU/trans-issue
// bound at ~71% packing, HBM 2.8%, 0 bank conflicts, no MFMA path (fp32
// scan, d_inner*d_state=32 too small for MFMA tiles to pay).

typedef float v2f __attribute__((ext_vector_type(2)));

#define TT 1024
#define TC 32
#define NSEGS 8
#define SEGLEN (TT / NSEGS)            // 128
#define NCHUNK (SEGLEN / TC)           // 4
#define NUM_PAIRS 36
#define NSEQ 2304

// per-(wave,half) staging layout (float/uint slots):
// DT [0,128) floats, DS [128,256) uints, BC [256,520) uints
#define DT_OFF 0
#define DS_OFF 128
#define BC_OFF 256
#define BC_STRIDE 33                   // half2 slots per BC row (bank spread)
#define PER_HALF_STRIDE 528            // floats; %32==16 -> halves bank-disjoint
#define PER_WAVE (2 * PER_HALF_STRIDE) // 1056 floats
#define STAGE_TOTAL (4 * PER_WAVE)     // 4224 floats = 16896 B

__device__ __forceinline__ float fast_silu(float v) {
    float e = __builtin_amdgcn_exp2f(v * -1.4426950408889634f);
    return v * __builtin_amdgcn_rcpf(1.0f + e);
}
// softplus, direct form: log(1+exp(v)). Safe: |v| <~ 20 here.
__device__ __forceinline__ float fast_softplus(float v) {
    float e = __builtin_amdgcn_exp2f(v * 1.4426950408889634f);
    return __builtin_amdgcn_logf(1.0f + e) * 0.6931471805599453f;
}
__device__ __forceinline__ uint pk_h2(float a, float b) {
    return __builtin_bit_cast(uint, __builtin_amdgcn_cvt_pkrtz(a, b));
}

__global__ __launch_bounds__(256, 4)
void pm_kernel(const float* __restrict__ raw,        // (N,2,T)
               const float* __restrict__ in_proj_w,  // (8,2)
               const float* __restrict__ conv_w,     // (4,2)
               const float* __restrict__ conv_b,     // (4)
               const float* __restrict__ x_proj_w,   // (17,4)
               const float* __restrict__ dt_proj_w,  // (4,1)
               const float* __restrict__ dt_proj_b,  // (4)
               const float* __restrict__ A_log,      // (4,8)
               const float* __restrict__ D_skip,     // (4)
               const float* __restrict__ out_proj_w, // (2,4)
               const float* __restrict__ proj_w,     // (16,2)
               const float* __restrict__ proj_b,     // (16)
               float* __restrict__ out)              // (64,16), pre-zeroed
{
    __shared__ float lds[STAGE_TOTAL];

    const int tid  = threadIdx.x;
    const int wid  = tid >> 6;        // wave 0..3
    const int lane = tid & 63;
    const int half = lane >> 5;
    const int lh   = lane & 31;       // pointwise: t-in-chunk; scan: ds = d*8+s
    const int g    = wid * 2 + half;  // segment 0..7 of THIS block's sequence
    const int n    = blockIdx.x;      // one sequence per block
    const float* rp = raw + (size_t)n * (2 * TT);

    float* hb = lds + wid * PER_WAVE + half * PER_HALF_STRIDE;

    // ---- weights (wave-uniform -> scalarized) ----
    float ip0[8], ip1[8];
#pragma unroll
    for (int j = 0; j < 8; ++j) { ip0[j] = in_proj_w[2*j]; ip1[j] = in_proj_w[2*j+1]; }
    float cw0[4], cw1[4], cbv[4], dpw[4], dpb[4], Dsk[4], ow0[4], ow1[4], xp0[4];
#pragma unroll
    for (int d = 0; d < 4; ++d) {
        cw0[d] = conv_w[2*d]; cw1[d] = conv_w[2*d+1]; cbv[d] = conv_b[d];
        dpw[d] = dt_proj_w[d]; dpb[d] = dt_proj_b[d];
        Dsk[d] = D_skip[d]; ow0[d] = out_proj_w[d]; ow1[d] = out_proj_w[4+d];
        xp0[d] = x_proj_w[d];
    }
    v2f xbc[8][4];  // {x_proj_w[1+s][d], x_proj_w[9+s][d]}
#pragma unroll
    for (int s = 0; s < 8; ++s)
#pragma unroll
        for (int d = 0; d < 4; ++d)
            xbc[s][d] = (v2f){x_proj_w[4*(1+s) + d], x_proj_w[4*(9+s) + d]};

    const float LOG2E = 1.4426950408889634f;
    // scan-role constants: lane lh -> (d,s)
    const int   d_idx = lh >> 3;
    const int   s_idx = lh & 7;
    const float A2ds  = -__expf(A_log[lh]) * LOG2E;   // a = exp2(dt * A2ds)
    const float owd0  = out_proj_w[d_idx];
    const float owd1  = out_proj_w[4 + d_idx];

    // hoisted scan read pointers (imm offsets inside the loop)
    const float* dtp = hb + DT_OFF + d_idx;                  // [t2*4]
    const uint*  dsp = (const uint*)(hb + DS_OFF) + d_idx;   // [t2*4]
    const uint*  bcp = (const uint*)(hb + BC_OFF) + s_idx * BC_STRIDE; // [t2]

    // segment-local affine reduction state (per ds lane)
    float A_run = 1.0f, hB = 0.0f, W = 0.0f, S = 0.0f;
    float sacc0 = 0.f, sacc1 = 0.f;                    // skip-term partials

    const int seg0 = g * SEGLEN;

    // prefetch chunk 0 raw samples (t and t-1, both channels)
    int t0 = seg0 + lh;
    float c0  = rp[t0];
    float c1  = rp[TT + t0];
    float c0m = (t0 > 0) ? rp[t0 - 1]      : 0.0f;     // causal pad at t==0
    float c1m = (t0 > 0) ? rp[TT + t0 - 1] : 0.0f;

    for (int chunk = 0; chunk < NCHUNK; ++chunk) {
        // software prefetch next chunk's raw
        float p0 = 0.f, p1 = 0.f, p0m = 0.f, p1m = 0.f;
        if (chunk + 1 < NCHUNK) {
            int tn = seg0 + (chunk + 1) * TC + lh;     // tn >= 32 -> tn-1 valid
            p0  = rp[tn];       p1  = rp[TT + tn];
            p0m = rp[tn - 1];   p1m = rp[TT + tn - 1];
        }

        // ---- pointwise: this lane handles t = seg0 + chunk*TC + lh ----
        float x[4], sz[4];
#pragma unroll
        for (int d = 0; d < 4; ++d) {
            float xz  = ip0[d]*c0  + ip1[d]*c1;
            float xm1 = ip0[d]*c0m + ip1[d]*c1m;
            float zv  = ip0[4+d]*c0 + ip1[4+d]*c1;
            float v   = xm1*cw0[d] + xz*cw1[d] + cbv[d];   // causal conv k=2
            x[d]  = fast_silu(v);
            sz[d] = fast_silu(zv);
        }

        float dtin = xp0[0]*x[0] + xp0[1]*x[1] + xp0[2]*x[2] + xp0[3]*x[3];

        v2f bc[8];
#pragma unroll
        for (int s = 0; s < 8; ++s) {
            v2f a = xbc[s][0] * (v2f){x[0], x[0]};
            a = __builtin_elementwise_fma(xbc[s][1], (v2f){x[1], x[1]}, a);
            a = __builtin_elementwise_fma(xbc[s][2], (v2f){x[2], x[2]}, a);
            bc[s] = __builtin_elementwise_fma(xbc[s][3], (v2f){x[3], x[3]}, a);
        }

        float dt[4];
#pragma unroll
        for (int d = 0; d < 4; ++d) {
            dt[d] = fast_softplus(dtin*dpw[d] + dpb[d]);
            float g2 = x[d] * Dsk[d] * sz[d];              // skip term
            sacc0 = fmaf(g2, ow0[d], sacc0);
            sacc1 = fmaf(g2, ow1[d], sacc1);
        }

        // stage: DT (float4, lane-consecutive), DS (uint4), BC (8x b32)
        *(float4*)(hb + DT_OFF + lh*4) = make_float4(dt[0], dt[1], dt[2], dt[3]);
        *(uint4*)((uint*)(hb + DS_OFF) + lh*4) =
            make_uint4(pk_h2(dt[0]*x[0], sz[0]), pk_h2(dt[1]*x[1], sz[1]),
                       pk_h2(dt[2]*x[2], sz[2]), pk_h2(dt[3]*x[3], sz[3]));
        uint* bcw = (uint*)(hb + BC_OFF) + lh;
#pragma unroll
        for (int s = 0; s < 8; ++s)
            bcw[s * BC_STRIDE] = pk_h2(bc[s].x, bc[s].y);

        // ---- scan: lane owns (d_idx, s_idx); local affine reduction ----
        // (same-wave LDS RAW: compiler orders via its own waitcnt insertion)
#pragma unroll
        for (int t2 = 0; t2 < TC; ++t2) {
            float dtv = dtp[t2*4];                          // broadcast b32
            uint  uds = dsp[t2*4];                          // half2(dtx, sz)
            uint  ubc = bcp[t2];                            // half2(B, C)
            __half2 prod = __hmul2(__builtin_bit_cast(__half2, uds),
                                   __builtin_bit_cast(__half2, ubc));
            float b = __half2float(__low2half(prod));       // dtx*B
            float q = __half2float(__high2half(prod));      // sz*C
            float a = __builtin_amdgcn_exp2f(dtv * A2ds);
            A_run *= a;                    // running product  П a
            hB = fmaf(a, hB, b);           // local scan, h_in = 0
            W  = fmaf(A_run, q, W);        // h_in-coupling coefficient
            S  = fmaf(hB, q, S);           // h_in-independent contribution
        }

        c0 = p0; c1 = p1; c0m = p0m; c1m = p1m;
    }

    // ---- cross-segment combine (aliases dead staging LDS, post-barrier) ----
    __syncthreads();
    float2* comb = (float2*)lds;                       // 8*32 float2 = 512 floats
    comb[g*32 + lh] = make_float2(A_run, hB);
    __syncthreads();

    // compose the segments before g to get this segment's h_in (g wave-uniform
    // per half; exec-masked loop, max 7 iters)
    float h_in = 0.0f;
#pragma unroll
    for (int gg = 0; gg < NSEGS - 1; ++gg) {
        if (gg < g) {
            float2 abg = comb[gg*32 + lh];
            h_in = fmaf(abg.x, h_in, abg.y);
        }
    }

    float F = fmaf(h_in, W, S);          // this segment's Σ_t h_t q_t for (d,s)
    float tot0 = fmaf(F, owd0, sacc0);
    float tot1 = fmaf(F, owd1, sacc1);
#pragma unroll
    for (int m = 16; m >= 1; m >>= 1) {  // reduce within the 32-lane half
        tot0 += __shfl_xor(tot0, m, 64);
        tot1 += __shfl_xor(tot1, m, 64);
    }
    float* part = lds + 512;             // past comb region
    if (lh == 0) {
        part[g*2]     = tot0;
        part[g*2 + 1] = tot1;
    }
    __syncthreads();

    // wave 0 lanes 0-15: sum segment partials, head projection, mean over pairs
    if (tid < 16) {
        float f0 = 0.f, f1 = 0.f;
#pragma unroll
        for (int gg = 0; gg < NSEGS; ++gg) {
            f0 += part[gg*2];
            f1 += part[gg*2 + 1];
        }
        f0 *= (1.0f / (float)TT);
        f1 *= (1.0f / (float)TT);
        float pv = f0*proj_w[2*tid] + f1*proj_w[2*tid + 1] + proj_b[tid];
        pv = fmaxf(pv, 0.0f);
        atomicAdd(out + (n / NUM_PAIRS) * 16 + tid, pv * (1.0f / NUM_PAIRS));
    }
}

extern "C" void kernel_launch(void* const* d_in, const int* in_sizes, int n_in,
                              void* d_out, int out_size, void* d_ws, size_t ws_size,
                              hipStream_t stream)
{
    const float* raw        = (const float*)d_in[0];
    const float* in_proj_w  = (const float*)d_in[1];
    const float* conv_w     = (const float*)d_in[2];
    const float* conv_b     = (const float*)d_in[3];
    const float* x_proj_w   = (const float*)d_in[4];
    const float* dt_proj_w  = (const float*)d_in[5];
    const float* dt_proj_b  = (const float*)d_in[6];
    const float* A_log      = (const float*)d_in[7];
    const float* D_skip     = (const float*)d_in[8];
    const float* out_proj_w = (const float*)d_in[9];
    const float* proj_w     = (const float*)d_in[10];
    const float* proj_b     = (const float*)d_in[11];

    // d_out is re-poisoned before every timed replay; zero it (atomicAdd sink)
    hipMemsetAsync(d_out, 0, (size_t)out_size * sizeof(float), stream);

    pm_kernel<<<dim3(NSEQ), dim3(256), 0, stream>>>(
        raw, in_proj_w, conv_w, conv_b, x_proj_w, dt_proj_w, dt_proj_b,
        A_log, D_skip, out_proj_w, proj_w, proj_b, (float*)d_out);
}